// Round 8
// baseline (5521.189 us; speedup 1.0000x reference)
//
#include <hip/hip_runtime.h>

typedef short short8 __attribute__((ext_vector_type(8)));
typedef float f32x4 __attribute__((ext_vector_type(4)));
typedef float f32x16 __attribute__((ext_vector_type(16)));
typedef int i32x4 __attribute__((ext_vector_type(4)));
typedef unsigned short u16;
typedef unsigned long long u64;

#define NBLK 256
#define BDIM 512
#define BB 64
#define TT 512
#define II 512
#define HH 1024
#define NCLS 1000
#define HBUF (BB*HH)

__device__ __forceinline__ u16 f2bf(float f) {
  union { float f; unsigned u; } v; v.f = f;
  unsigned u = v.u;
  u += 0x7fffu + ((u >> 16) & 1u);   // RNE
  return (u16)(u >> 16);
}

__device__ __forceinline__ short8 cvt8(f32x4 a, f32x4 b) {
  short8 v;
  v[0] = (short)f2bf(a[0]); v[1] = (short)f2bf(a[1]);
  v[2] = (short)f2bf(a[2]); v[3] = (short)f2bf(a[3]);
  v[4] = (short)f2bf(b[0]); v[5] = (short)f2bf(b[1]);
  v[6] = (short)f2bf(b[2]); v[7] = (short)f2bf(b[3]);
  return v;
}

__device__ __forceinline__ unsigned ld_rlx(const unsigned* p) {
  return __hip_atomic_load(p, __ATOMIC_RELAXED, __HIP_MEMORY_SCOPE_AGENT);
}
__device__ __forceinline__ void st_rlx(unsigned* p, unsigned v) {
  __hip_atomic_store(p, v, __ATOMIC_RELAXED, __HIP_MEMORY_SCOPE_AGENT);
}

// x f32 -> bf16 pre-pass (tier A)
__global__ void cvt_x(const float* __restrict__ x, u16* __restrict__ xb, int n8) {
  int i = blockIdx.x * blockDim.x + threadIdx.x;
  const int stride = gridDim.x * blockDim.x;
  for (; i < n8; i += stride) {
    f32x4 a = ((const f32x4*)x)[2 * i];
    f32x4 b = ((const f32x4*)x)[2 * i + 1];
    ((short8*)xb)[i] = cvt8(a, b);
  }
}

// ---- fragment-run helpers; breg stays in registers (static indices only) ----

// coherent run: batches of 8 global_load_dwordx4 sc0 sc1, vmcnt(0) per batch
template<int N, int B0, int MH>
__device__ __forceinline__ void run_coh(const u16* lanep,
                                        const short8 (&breg)[MH], f32x16& acc) {
  static_assert(N % 8 == 0, "");
#pragma unroll
  for (int c = 0; c < N; c += 8) {
    i32x4 av[8];
#pragma unroll
    for (int i = 0; i < 8; ++i) {
      const u16* p = lanep + (c + i) * 16;
      asm volatile("global_load_dwordx4 %0, %1, off sc0 sc1"
                   : "=v"(av[i]) : "v"(p));
    }
    asm volatile("s_waitcnt vmcnt(0)" ::: "memory");
    __builtin_amdgcn_sched_barrier(0);
#pragma unroll
    for (int i = 0; i < 8; ++i) {
      union { i32x4 q; short8 s; } u; u.q = av[i];
      acc = __builtin_amdgcn_mfma_f32_32x32x16_bf16(u.s, breg[B0 + c + i], acc, 0, 0, 0);
    }
  }
}

// plain cached bf16 run (L0 x-section, tier A)
template<int N, int B0, int MH>
__device__ __forceinline__ void run_pb(const u16* lanep,
                                       const short8 (&breg)[MH], f32x16& acc) {
#pragma unroll
  for (int i = 0; i < N; ++i) {
    short8 av = *(const short8*)(lanep + i * 16);
    acc = __builtin_amdgcn_mfma_f32_32x32x16_bf16(av, breg[B0 + i], acc, 0, 0, 0);
  }
}

// plain cached f32 run + convert (L0 x-section, tier B)
template<int N, int B0, int MH>
__device__ __forceinline__ void run_pf(const float* lanep,
                                       const short8 (&breg)[MH], f32x16& acc) {
#pragma unroll
  for (int i = 0; i < N; ++i) {
    short8 av = cvt8(*(const f32x4*)(lanep + i * 16),
                     *(const f32x4*)(lanep + i * 16 + 4));
    acc = __builtin_amdgcn_mfma_f32_32x32x16_bf16(av, breg[B0 + i], acc, 0, 0, 0);
  }
}

// Decoupled persistent 2-layer LSTM, weights-in-registers edition.
// Blocks [0,128)=L0, [128,256)=L1; 8 waves = 2 M-halves x 4 K-quarters.
// MFMA 32x32x16: one B-fragment spans all 32 gate rows -> per-wave B slice
// (L1: 32 frags = 128 VGPR, L0: 24) loaded from LDS ONCE in the prologue.
// Steady-state loop: zero ds_reads; coherent batched A loads; K-partials to a
// write-only g4 buffer aliased onto the dead weight-LDS region.
template<bool XBF>
__global__ __launch_bounds__(BDIM, 2) void lstm2_fused(
    const float* __restrict__ x, const u16* __restrict__ xb,
    const float* __restrict__ Wih0, const float* __restrict__ Whh0,
    const float* __restrict__ bih0, const float* __restrict__ bhh0,
    const float* __restrict__ Wih1, const float* __restrict__ Whh1,
    const float* __restrict__ bih1, const float* __restrict__ bhh1,
    u16* __restrict__ ring,          // 3 x [64][1024] bf16 (h0)
    u16* __restrict__ h1buf,         // 2 x [64][1024] bf16 (h1)
    float* __restrict__ h1f,
    unsigned* __restrict__ bar)
{
  __shared__ u16 wlds[32 * 2048];        // 128 KB weight staging (prologue only)
  __shared__ float blds[32];             // fused biases
  // K-partial buffer aliased onto wlds tail: L0 uses wlds[0,98304) only;
  // L1 never reads wlds after the prologue. [4][64][32] f32 = 32 KB.
  float (*g4)[64][32] = (float(*)[64][32])((char*)wlds + 98304);

  const bool isL1 = (blockIdx.x >= 128);
  const int wgl = isL1 ? (int)blockIdx.x - 128 : (int)blockIdx.x;
  const int j0 = wgl * 8;                // first hidden unit owned
  const int KX = isL1 ? HH : II;         // input-section K
  const int RL = KX + HH;                // row length: 2048 / 1536
  const int ROWB = RL * 2;               // row bytes in LDS
  const float* Wih = isL1 ? Wih1 : Wih0;
  const float* Whh = isL1 ? Whh1 : Whh0;

  // ---- stage weights into LDS (f32 -> bf16), swizzle byte ^= (row&7)<<4 ----
  {
    const int cpr = RL / 8;
    for (int idx = threadIdx.x; idx < 32 * cpr; idx += BDIM) {
      int n = idx / cpr, cb = idx - n * cpr;
      int r = ((n >> 3) << 10) + j0 + (n & 7);   // global gate row: gate*1024 + j
      int k = cb * 8;
      const float* src = (k < KX) ? (Wih + (size_t)r * KX + k)
                                  : (Whh + (size_t)r * HH + (k - KX));
      f32x4 a = *(const f32x4*)src;
      f32x4 b = *(const f32x4*)(src + 4);
      short8 v = cvt8(a, b);
      unsigned byte = (unsigned)(n * ROWB + k * 2) ^ ((unsigned)(n & 7) << 4);
      *(short8*)((char*)wlds + byte) = v;
    }
    if (threadIdx.x < 32) {
      int n = threadIdx.x;
      int r = ((n >> 3) << 10) + j0 + (n & 7);
      blds[n] = (isL1 ? bih1[r] : bih0[r]) + (isL1 ? bhh1[r] : bhh0[r]);
    }
  }
  __syncthreads();

  const int lane = threadIdx.x & 63;
  const int wid = threadIdx.x >> 6;      // 8 waves
  const int mp = wid & 1, kq = wid >> 1; // 2 M-halves x 4 K-quarters
  const int row_a = mp * 32 + (lane & 31);
  const int sub8 = (lane >> 5) << 3;     // k sub-offset within a 16-k fragment
  const char* wch = (const char*)wlds;

  const int tb = threadIdx.x >> 3, tj = threadIdx.x & 7;  // tail (batch, unit)

  unsigned* const arrA = bar;           // L0 arrive
  unsigned* const relA = bar + 64;      // L0 release / producer flag
  unsigned* const arrB = bar + 256;     // L1 arrive
  unsigned* const relB = bar + 320;     // L1 release / consumer flag

  float c_state = 0.f;

  // tail: sum 4 K-partials + bias, nonlinearity, c/h update, coherent h store
  auto step_tail = [&](const f32x16& acc, u16* hout, bool wf) {
    const int col = lane & 31;
    const int rbase = mp * 32 + ((lane >> 5) << 2);
#pragma unroll
    for (int r = 0; r < 16; ++r) {
      int brow = rbase + (r & 3) + ((r >> 2) << 3);
      g4[kq][brow][col] = acc[r];
    }
    __syncthreads();
    float gv[4];
#pragma unroll
    for (int g = 0; g < 4; ++g)
      gv[g] = g4[0][tb][g * 8 + tj] + g4[1][tb][g * 8 + tj]
            + g4[2][tb][g * 8 + tj] + g4[3][tb][g * 8 + tj] + blds[g * 8 + tj];
    float gi = 1.f / (1.f + __expf(-gv[0]));
    float gf = 1.f / (1.f + __expf(-gv[1]));
    float e2 = __expf(2.f * fminf(15.f, fmaxf(-15.f, gv[2])));
    float gg = (e2 - 1.f) / (e2 + 1.f);
    float go = 1.f / (1.f + __expf(-gv[3]));
    c_state = gf * c_state + gi * gg;
    float e2c = __expf(2.f * fminf(15.f, fmaxf(-15.f, c_state)));
    float th = (e2c - 1.f) / (e2c + 1.f);
    float hval = go * th;
    unsigned hu = (unsigned)f2bf(hval);
    unsigned nbv = (unsigned)__shfl_xor((int)hu, 1);
    if ((tj & 1) == 0) {
      unsigned packed = hu | (nbv << 16);
      unsigned* dst = (unsigned*)(hout + (size_t)tb * HH + j0 + tj);
      st_rlx(dst, packed);
    }
    if (wf) h1f[(size_t)tb * HH + j0 + tj] = hval;
  };

  if (!isL1) {
    // ================= layer 0: HALF=24 frags/wave (96 total, 32 = x) =========
    short8 breg[24];
#pragma unroll
    for (int i = 0; i < 24; ++i) {
      int k = (kq * 24 + i) * 16 + sub8;
      unsigned byte = ((unsigned)((lane & 31) * ROWB + k * 2))
                      ^ ((unsigned)(lane & 7) << 4);
      breg[i] = *(const short8*)(wch + byte);
    }
    __syncthreads();                     // all breg reads done before g4 reuse

    for (int t = 0; t < TT; ++t) {
      if (t >= 3) {                      // ring flow control: slot t%3 free?
        if (threadIdx.x == 0)
          while (ld_rlx(relB) < (unsigned)(t - 2)) __builtin_amdgcn_s_sleep(2);
        __syncthreads();
      }
      f32x16 acc = {};
      const u16* hb = ring + (size_t)((t + 2) % 3) * HBUF + (size_t)row_a * HH;
      if (XBF) {
        const u16* xl = xb + (size_t)t * II + (size_t)row_a * ((size_t)TT * II)
                        + kq * 384 + sub8;
        if (kq == 0)      run_pb<24, 0>(xl, breg, acc);
        else if (kq == 1) { run_pb<8, 0>(xl, breg, acc);
                            run_coh<16, 8>(hb + 0 + sub8, breg, acc); }
        else if (kq == 2) run_coh<24, 0>(hb + 256 + sub8, breg, acc);
        else              run_coh<24, 0>(hb + 640 + sub8, breg, acc);
      } else {
        const float* xl = x + (size_t)t * II + (size_t)row_a * ((size_t)TT * II)
                          + kq * 384 + sub8;
        if (kq == 0)      run_pf<24, 0>(xl, breg, acc);
        else if (kq == 1) { run_pf<8, 0>(xl, breg, acc);
                            run_coh<16, 8>(hb + 0 + sub8, breg, acc); }
        else if (kq == 2) run_coh<24, 0>(hb + 256 + sub8, breg, acc);
        else              run_coh<24, 0>(hb + 640 + sub8, breg, acc);
      }
      step_tail(acc, ring + (size_t)(t % 3) * HBUF, false);
      // barrier-A (128 L0 blocks); release doubles as producer flag for L1
      __syncthreads();
      if (threadIdx.x == 0) {
        unsigned old = atomicAdd(arrA, 1u);
        if (old == (unsigned)(128 * (t + 1) - 1)) st_rlx(relA, (unsigned)(t + 1));
        else if (t < TT - 1)
          while (ld_rlx(relA) < (unsigned)(t + 1)) __builtin_amdgcn_s_sleep(2);
      }
      __syncthreads();
    }
  } else {
    // ================= layer 1: HALF=32 frags/wave (128 total, 64 = h0) =======
    short8 breg[32];
#pragma unroll
    for (int i = 0; i < 32; ++i) {
      int k = (kq * 32 + i) * 16 + sub8;
      unsigned byte = ((unsigned)((lane & 31) * ROWB + k * 2))
                      ^ ((unsigned)(lane & 7) << 4);
      breg[i] = *(const short8*)(wch + byte);
    }
    __syncthreads();                     // all breg reads done before g4 reuse

    for (int t = 0; t < TT; ++t) {
      if (threadIdx.x == 0)              // producer flag: h0(t) visible?
        while (ld_rlx(relA) < (unsigned)(t + 1)) __builtin_amdgcn_s_sleep(2);
      __syncthreads();
      f32x16 acc = {};
      const u16* lp;
      if (kq < 2)                        // input section: h0(t) = ring slot t%3
        lp = ring + (size_t)(t % 3) * HBUF + (size_t)row_a * HH + kq * 512 + sub8;
      else                               // recurrent: h1(t-1)
        lp = h1buf + (size_t)((t + 1) & 1) * HBUF + (size_t)row_a * HH
             + (kq - 2) * 512 + sub8;
      run_coh<32, 0>(lp, breg, acc);
      step_tail(acc, h1buf + (size_t)(t & 1) * HBUF, t == TT - 1);
      if (t < TT - 1) {                  // barrier-B; release doubles as consumer flag
        __syncthreads();
        if (threadIdx.x == 0) {
          unsigned old = atomicAdd(arrB, 1u);
          if (old == (unsigned)(128 * (t + 1) - 1)) st_rlx(relB, (unsigned)(t + 1));
          else
            while (ld_rlx(relB) < (unsigned)(t + 1)) __builtin_amdgcn_s_sleep(2);
        }
        __syncthreads();
      }
    }
  }
}

// out[b][c] = sum_k h1f[b][k] * Wd[c][k] + bd[c]   (all f32)
__global__ void dense_out(const float* __restrict__ h1, const float* __restrict__ Wd,
                          const float* __restrict__ bd, float* __restrict__ out)
{
  const int b  = threadIdx.x & 63;       // batch
  const int cl = threadIdx.x >> 6;
  const int cc = blockIdx.x * 4 + cl;    // class (250*4 = 1000)
  float acc = 0.f;
  const float* hrow = h1 + (size_t)b * HH;
  const float* wrow = Wd + (size_t)cc * HH;
#pragma unroll 8
  for (int k = 0; k < HH; k += 4) {
    f32x4 hv = *(const f32x4*)(hrow + k);
    f32x4 wv = *(const f32x4*)(wrow + k);
    acc += hv[0] * wv[0] + hv[1] * wv[1] + hv[2] * wv[2] + hv[3] * wv[3];
  }
  out[(size_t)b * NCLS + cc] = acc + bd[cc];
}

extern "C" void kernel_launch(void* const* d_in, const int* in_sizes, int n_in,
                              void* d_out, int out_size, void* d_ws, size_t ws_size,
                              hipStream_t stream)
{
  (void)in_sizes; (void)n_in; (void)out_size;
  const float* x    = (const float*)d_in[0];
  const float* Wih0 = (const float*)d_in[1];
  const float* Whh0 = (const float*)d_in[2];
  const float* bih0 = (const float*)d_in[3];
  const float* bhh0 = (const float*)d_in[4];
  const float* Wih1 = (const float*)d_in[5];
  const float* Whh1 = (const float*)d_in[6];
  const float* bih1 = (const float*)d_in[7];
  const float* bhh1 = (const float*)d_in[8];
  const float* Wd   = (const float*)d_in[9];
  const float* bd   = (const float*)d_in[10];

  unsigned* bar = (unsigned*)d_ws;                       // 4 KB barrier/flag words
  float* h1f  = (float*)((char*)d_ws + 4096);            // 256 KB
  u16* h1buf  = (u16*)((char*)d_ws + 272 * 1024);        // 2 x 128 KB
  u16* ring   = (u16*)((char*)d_ws + 528 * 1024);        // 3 x 128 KB
  u16* xb     = (u16*)((char*)d_ws + (1u << 20));        // 33.6 MB (tier A)

  const size_t needA = (1u << 20) + (size_t)BB * TT * II * 2;
  const bool tierA = (ws_size >= needA);

  // zero bars + h buffers every launch (graph-replay deterministic)
  hipMemsetAsync(d_ws, 0, 912 * 1024, stream);

  if (tierA) {
    hipLaunchKernelGGL(cvt_x, dim3(2048), dim3(256), 0, stream,
                       x, xb, (int)((size_t)BB * TT * II / 8));
    hipLaunchKernelGGL((lstm2_fused<true>), dim3(NBLK), dim3(BDIM), 0, stream,
                       x, xb, Wih0, Whh0, bih0, bhh0, Wih1, Whh1, bih1, bhh1,
                       ring, h1buf, h1f, bar);
  } else {
    hipLaunchKernelGGL((lstm2_fused<false>), dim3(NBLK), dim3(BDIM), 0, stream,
                       x, xb, Wih0, Whh0, bih0, bhh0, Wih1, Whh1, bih1, bhh1,
                       ring, h1buf, h1f, bar);
  }
  hipLaunchKernelGGL(dense_out, dim3(250), dim3(256), 0, stream, h1f, Wd, bd,
                     (float*)d_out);
}

// Round 9
// 4866.272 us; speedup vs baseline: 1.1346x; 1.1346x over previous
//
#include <hip/hip_runtime.h>

typedef short short8 __attribute__((ext_vector_type(8)));
typedef float f32x4 __attribute__((ext_vector_type(4)));
typedef float f32x16 __attribute__((ext_vector_type(16)));
typedef int i32x4 __attribute__((ext_vector_type(4)));
typedef unsigned short u16;
typedef unsigned long long u64;

#define NBLK 256
#define BDIM 512
#define BB 64
#define TT 512
#define II 512
#define HH 1024
#define NCLS 1000
#define HBUF (BB*HH)

__device__ __forceinline__ u16 f2bf(float f) {
  union { float f; unsigned u; } v; v.f = f;
  unsigned u = v.u;
  u += 0x7fffu + ((u >> 16) & 1u);   // RNE
  return (u16)(u >> 16);
}

__device__ __forceinline__ short8 cvt8(f32x4 a, f32x4 b) {
  short8 v;
  v[0] = (short)f2bf(a[0]); v[1] = (short)f2bf(a[1]);
  v[2] = (short)f2bf(a[2]); v[3] = (short)f2bf(a[3]);
  v[4] = (short)f2bf(b[0]); v[5] = (short)f2bf(b[1]);
  v[6] = (short)f2bf(b[2]); v[7] = (short)f2bf(b[3]);
  return v;
}

__device__ __forceinline__ unsigned ld_rlx(const unsigned* p) {
  return __hip_atomic_load(p, __ATOMIC_RELAXED, __HIP_MEMORY_SCOPE_AGENT);
}
__device__ __forceinline__ void st_rlx(unsigned* p, unsigned v) {
  __hip_atomic_store(p, v, __ATOMIC_RELAXED, __HIP_MEMORY_SCOPE_AGENT);
}
// wave-level flag wait: all lanes poll one address (single coalesced request)
__device__ __forceinline__ void wave_wait_ge(const unsigned* p, unsigned tgt) {
  while (ld_rlx(p) < tgt) __builtin_amdgcn_s_sleep(1);
}

// x f32 -> bf16 pre-pass (tier A)
__global__ void cvt_x(const float* __restrict__ x, u16* __restrict__ xb, int n8) {
  int i = blockIdx.x * blockDim.x + threadIdx.x;
  const int stride = gridDim.x * blockDim.x;
  for (; i < n8; i += stride) {
    f32x4 a = ((const f32x4*)x)[2 * i];
    f32x4 b = ((const f32x4*)x)[2 * i + 1];
    ((short8*)xb)[i] = cvt8(a, b);
  }
}

// ---- coherent fragment run: 2-deep pipelined batches, counted vmcnt ----
#define ISSUE8(arr, OFF)                                                     \
  _Pragma("unroll") for (int i_ = 0; i_ < 8; ++i_)                           \
    asm volatile("global_load_dwordx4 %0, %1, off sc0 sc1"                   \
                 : "=v"(arr[i_]) : "v"(lanep + ((OFF) + i_) * 16));
#define MFMA8(arr, OFF)                                                      \
  _Pragma("unroll") for (int i_ = 0; i_ < 8; ++i_) {                         \
    union { i32x4 q; short8 s; } u_; u_.q = arr[i_];                         \
    acc = __builtin_amdgcn_mfma_f32_32x32x16_bf16(u_.s, breg[B0 + (OFF) + i_],\
                                                  acc, 0, 0, 0); }
#define VMWAIT0 asm volatile("s_waitcnt vmcnt(0)" ::: "memory")
#define VMWAIT8 asm volatile("s_waitcnt vmcnt(8)" ::: "memory")
#define SCHEDB  __builtin_amdgcn_sched_barrier(0)

template<int N, int B0, int MH>
__device__ __forceinline__ void run_coh(const u16* lanep,
                                        const short8 (&breg)[MH], f32x16& acc) {
  static_assert(N == 8 || N == 16 || N == 24 || N == 32, "");
  i32x4 avA[8], avB[8];
  if constexpr (N == 8) {
    ISSUE8(avA, 0);
    VMWAIT0; SCHEDB; MFMA8(avA, 0);
  } else if constexpr (N == 16) {
    ISSUE8(avA, 0); ISSUE8(avB, 8);
    VMWAIT8; SCHEDB; MFMA8(avA, 0);
    VMWAIT0; SCHEDB; MFMA8(avB, 8);
  } else if constexpr (N == 24) {
    ISSUE8(avA, 0); ISSUE8(avB, 8);
    VMWAIT8; SCHEDB; MFMA8(avA, 0); ISSUE8(avA, 16);
    VMWAIT8; SCHEDB; MFMA8(avB, 8);
    VMWAIT0; SCHEDB; MFMA8(avA, 16);
  } else {
    ISSUE8(avA, 0); ISSUE8(avB, 8);
    VMWAIT8; SCHEDB; MFMA8(avA, 0); ISSUE8(avA, 16);
    VMWAIT8; SCHEDB; MFMA8(avB, 8); ISSUE8(avB, 24);
    VMWAIT8; SCHEDB; MFMA8(avA, 16);
    VMWAIT0; SCHEDB; MFMA8(avB, 24);
  }
}

// plain cached bf16 run (L0 x-section, tier A)
template<int N, int B0, int MH>
__device__ __forceinline__ void run_pb(const u16* lanep,
                                       const short8 (&breg)[MH], f32x16& acc) {
#pragma unroll
  for (int i = 0; i < N; ++i) {
    short8 av = *(const short8*)(lanep + i * 16);
    acc = __builtin_amdgcn_mfma_f32_32x32x16_bf16(av, breg[B0 + i], acc, 0, 0, 0);
  }
}

// plain cached f32 run + convert (L0 x-section, tier B)
template<int N, int B0, int MH>
__device__ __forceinline__ void run_pf(const float* lanep,
                                       const short8 (&breg)[MH], f32x16& acc) {
#pragma unroll
  for (int i = 0; i < N; ++i) {
    short8 av = cvt8(*(const f32x4*)(lanep + i * 16),
                     *(const f32x4*)(lanep + i * 16 + 4));
    acc = __builtin_amdgcn_mfma_f32_32x32x16_bf16(av, breg[B0 + i], acc, 0, 0, 0);
  }
}

// Decoupled persistent 2-layer LSTM, split-barrier edition.
// Blocks [0,128)=L0, [128,256)=L1; 8 waves = 2 M-halves x 4 K-quarters;
// weights in registers (32x32x16 MFMA). Blocks ARRIVE at the end of a step but
// never wait there; the next step's recurrent waves wait wave-locally on the
// release flag, overlapped with the independent input-section compute.
template<bool XBF>
__global__ __launch_bounds__(BDIM, 2) void lstm2_fused(
    const float* __restrict__ x, const u16* __restrict__ xb,
    const float* __restrict__ Wih0, const float* __restrict__ Whh0,
    const float* __restrict__ bih0, const float* __restrict__ bhh0,
    const float* __restrict__ Wih1, const float* __restrict__ Whh1,
    const float* __restrict__ bih1, const float* __restrict__ bhh1,
    u16* __restrict__ ring,          // 3 x [64][1024] bf16 (h0)
    u16* __restrict__ h1buf,         // 2 x [64][1024] bf16 (h1)
    float* __restrict__ h1f,
    unsigned* __restrict__ bar)
{
  __shared__ u16 wlds[32 * 2048];        // 128 KB weight staging (prologue only)
  __shared__ float blds[32];             // fused biases
  float (*g4)[64][32] = (float(*)[64][32])((char*)wlds + 98304);  // aliased 32 KB

  const bool isL1 = (blockIdx.x >= 128);
  const int wgl = isL1 ? (int)blockIdx.x - 128 : (int)blockIdx.x;
  const int j0 = wgl * 8;
  const int KX = isL1 ? HH : II;
  const int RL = KX + HH;                // 2048 / 1536
  const int ROWB = RL * 2;
  const float* Wih = isL1 ? Wih1 : Wih0;
  const float* Whh = isL1 ? Whh1 : Whh0;

  // ---- stage weights into LDS (f32 -> bf16), swizzle byte ^= (row&7)<<4 ----
  {
    const int cpr = RL / 8;
    for (int idx = threadIdx.x; idx < 32 * cpr; idx += BDIM) {
      int n = idx / cpr, cb = idx - n * cpr;
      int r = ((n >> 3) << 10) + j0 + (n & 7);
      int k = cb * 8;
      const float* src = (k < KX) ? (Wih + (size_t)r * KX + k)
                                  : (Whh + (size_t)r * HH + (k - KX));
      f32x4 a = *(const f32x4*)src;
      f32x4 b = *(const f32x4*)(src + 4);
      short8 v = cvt8(a, b);
      unsigned byte = (unsigned)(n * ROWB + k * 2) ^ ((unsigned)(n & 7) << 4);
      *(short8*)((char*)wlds + byte) = v;
    }
    if (threadIdx.x < 32) {
      int n = threadIdx.x;
      int r = ((n >> 3) << 10) + j0 + (n & 7);
      blds[n] = (isL1 ? bih1[r] : bih0[r]) + (isL1 ? bhh1[r] : bhh0[r]);
    }
  }
  __syncthreads();

  const int lane = threadIdx.x & 63;
  const int wid = threadIdx.x >> 6;
  const int mp = wid & 1, kq = wid >> 1; // 2 M-halves x 4 K-quarters
  const int row_a = mp * 32 + (lane & 31);
  const int sub8 = (lane >> 5) << 3;
  const char* wch = (const char*)wlds;

  const int tb = threadIdx.x >> 3, tj = threadIdx.x & 7;

  unsigned* const arrA = bar;           // L0 arrive counter
  unsigned* const relA = bar + 64;      // "h0(t) visible" <=> relA >= t+1
  unsigned* const arrB = bar + 256;     // L1 arrive counter
  unsigned* const relB = bar + 320;     // "h1(t) visible" <=> relB >= t+1

  float c_state = 0.f;

  // tail: K-partial combine, gates, c/h update, coherent h store, arrive.
  auto step_tail = [&](const f32x16& acc, u16* hout, unsigned ringtgt, bool wf,
                       unsigned* arr, unsigned* rel, int t) {
    const int col = lane & 31;
    const int rbase = mp * 32 + ((lane >> 5) << 2);
#pragma unroll
    for (int r = 0; r < 16; ++r) {
      int brow = rbase + (r & 3) + ((r >> 2) << 3);
      g4[kq][brow][col] = acc[r];
    }
    __syncthreads();
    float gv[4];
#pragma unroll
    for (int g = 0; g < 4; ++g)
      gv[g] = g4[0][tb][g * 8 + tj] + g4[1][tb][g * 8 + tj]
            + g4[2][tb][g * 8 + tj] + g4[3][tb][g * 8 + tj] + blds[g * 8 + tj];
    float gi = 1.f / (1.f + __expf(-gv[0]));
    float gf = 1.f / (1.f + __expf(-gv[1]));
    float e2 = __expf(2.f * fminf(15.f, fmaxf(-15.f, gv[2])));
    float gg = (e2 - 1.f) / (e2 + 1.f);
    float go = 1.f / (1.f + __expf(-gv[3]));
    c_state = gf * c_state + gi * gg;
    float e2c = __expf(2.f * fminf(15.f, fmaxf(-15.f, c_state)));
    float th = (e2c - 1.f) / (e2c + 1.f);
    float hval = go * th;
    if (ringtgt) wave_wait_ge(relB, ringtgt);   // L0 ring slot reuse guard
    unsigned hu = (unsigned)f2bf(hval);
    unsigned nbv = (unsigned)__shfl_xor((int)hu, 1);
    if ((tj & 1) == 0) {
      unsigned packed = hu | (nbv << 16);
      unsigned* dst = (unsigned*)(hout + (size_t)tb * HH + j0 + tj);
      st_rlx(dst, packed);
    }
    if (wf) h1f[(size_t)tb * HH + j0 + tj] = hval;
    __syncthreads();                    // drains h stores (vmcnt) wave-by-wave
    if (threadIdx.x == 0) {             // arrive; closer posts release. NO wait.
      unsigned old = atomicAdd(arr, 1u);
      if (old == (unsigned)(128 * (t + 1) - 1)) st_rlx(rel, (unsigned)(t + 1));
    }
  };

  if (!isL1) {
    // ================= layer 0: 24 frags/wave; x-section needs no flag =======
    short8 breg[24];
#pragma unroll
    for (int i = 0; i < 24; ++i) {
      int k = (kq * 24 + i) * 16 + sub8;
      unsigned byte = ((unsigned)((lane & 31) * ROWB + k * 2))
                      ^ ((unsigned)(lane & 7) << 4);
      breg[i] = *(const short8*)(wch + byte);
    }
    __syncthreads();                     // breg reads done before g4 aliasing

    for (int t = 0; t < TT; ++t) {
      f32x16 acc = {};
      const u16* hb = ring + (size_t)((t + 2) % 3) * HBUF + (size_t)row_a * HH;
      if (XBF) {
        const u16* xl = xb + (size_t)t * II + (size_t)row_a * ((size_t)TT * II)
                        + kq * 384 + sub8;
        if (kq == 0)      run_pb<24, 0>(xl, breg, acc);
        else if (kq == 1) { run_pb<8, 0>(xl, breg, acc);
                            wave_wait_ge(relA, (unsigned)t);
                            run_coh<16, 8>(hb + 0 + sub8, breg, acc); }
        else if (kq == 2) { wave_wait_ge(relA, (unsigned)t);
                            run_coh<24, 0>(hb + 256 + sub8, breg, acc); }
        else              { wave_wait_ge(relA, (unsigned)t);
                            run_coh<24, 0>(hb + 640 + sub8, breg, acc); }
      } else {
        const float* xl = x + (size_t)t * II + (size_t)row_a * ((size_t)TT * II)
                          + kq * 384 + sub8;
        if (kq == 0)      run_pf<24, 0>(xl, breg, acc);
        else if (kq == 1) { run_pf<8, 0>(xl, breg, acc);
                            wave_wait_ge(relA, (unsigned)t);
                            run_coh<16, 8>(hb + 0 + sub8, breg, acc); }
        else if (kq == 2) { wave_wait_ge(relA, (unsigned)t);
                            run_coh<24, 0>(hb + 256 + sub8, breg, acc); }
        else              { wave_wait_ge(relA, (unsigned)t);
                            run_coh<24, 0>(hb + 640 + sub8, breg, acc); }
      }
      step_tail(acc, ring + (size_t)(t % 3) * HBUF,
                (t >= 3) ? (unsigned)(t - 2) : 0u, false, arrA, relA, t);
    }
  } else {
    // ================= layer 1: 32 frags/wave; input half waits only on relA ==
    short8 breg[32];
#pragma unroll
    for (int i = 0; i < 32; ++i) {
      int k = (kq * 32 + i) * 16 + sub8;
      unsigned byte = ((unsigned)((lane & 31) * ROWB + k * 2))
                      ^ ((unsigned)(lane & 7) << 4);
      breg[i] = *(const short8*)(wch + byte);
    }
    __syncthreads();                     // breg reads done before g4 aliasing

    for (int t = 0; t < TT; ++t) {
      f32x16 acc = {};
      if (kq < 2) {                      // input: h0(t) = ring slot t%3
        wave_wait_ge(relA, (unsigned)(t + 1));
        const u16* lp = ring + (size_t)(t % 3) * HBUF + (size_t)row_a * HH
                        + kq * 512 + sub8;
        run_coh<32, 0>(lp, breg, acc);
      } else {                           // recurrent: h1(t-1)
        wave_wait_ge(relB, (unsigned)t);
        const u16* lp = h1buf + (size_t)((t + 1) & 1) * HBUF
                        + (size_t)row_a * HH + (kq - 2) * 512 + sub8;
        run_coh<32, 0>(lp, breg, acc);
      }
      step_tail(acc, h1buf + (size_t)(t & 1) * HBUF, 0u, t == TT - 1,
                arrB, relB, t);
    }
  }
}

// out[b][c] = sum_k h1f[b][k] * Wd[c][k] + bd[c]   (all f32)
__global__ void dense_out(const float* __restrict__ h1, const float* __restrict__ Wd,
                          const float* __restrict__ bd, float* __restrict__ out)
{
  const int b  = threadIdx.x & 63;
  const int cl = threadIdx.x >> 6;
  const int cc = blockIdx.x * 4 + cl;    // class (250*4 = 1000)
  float acc = 0.f;
  const float* hrow = h1 + (size_t)b * HH;
  const float* wrow = Wd + (size_t)cc * HH;
#pragma unroll 8
  for (int k = 0; k < HH; k += 4) {
    f32x4 hv = *(const f32x4*)(hrow + k);
    f32x4 wv = *(const f32x4*)(wrow + k);
    acc += hv[0] * wv[0] + hv[1] * wv[1] + hv[2] * wv[2] + hv[3] * wv[3];
  }
  out[(size_t)b * NCLS + cc] = acc + bd[cc];
}

extern "C" void kernel_launch(void* const* d_in, const int* in_sizes, int n_in,
                              void* d_out, int out_size, void* d_ws, size_t ws_size,
                              hipStream_t stream)
{
  (void)in_sizes; (void)n_in; (void)out_size;
  const float* x    = (const float*)d_in[0];
  const float* Wih0 = (const float*)d_in[1];
  const float* Whh0 = (const float*)d_in[2];
  const float* bih0 = (const float*)d_in[3];
  const float* bhh0 = (const float*)d_in[4];
  const float* Wih1 = (const float*)d_in[5];
  const float* Whh1 = (const float*)d_in[6];
  const float* bih1 = (const float*)d_in[7];
  const float* bhh1 = (const float*)d_in[8];
  const float* Wd   = (const float*)d_in[9];
  const float* bd   = (const float*)d_in[10];

  unsigned* bar = (unsigned*)d_ws;                       // 4 KB barrier/flag words
  float* h1f  = (float*)((char*)d_ws + 4096);            // 256 KB
  u16* h1buf  = (u16*)((char*)d_ws + 272 * 1024);        // 2 x 128 KB
  u16* ring   = (u16*)((char*)d_ws + 528 * 1024);        // 3 x 128 KB
  u16* xb     = (u16*)((char*)d_ws + (1u << 20));        // 33.6 MB (tier A)

  const size_t needA = (1u << 20) + (size_t)BB * TT * II * 2;
  const bool tierA = (ws_size >= needA);

  // zero bars + h buffers every launch (graph-replay deterministic)
  hipMemsetAsync(d_ws, 0, 912 * 1024, stream);

  if (tierA) {
    hipLaunchKernelGGL(cvt_x, dim3(2048), dim3(256), 0, stream,
                       x, xb, (int)((size_t)BB * TT * II / 8));
    hipLaunchKernelGGL((lstm2_fused<true>), dim3(NBLK), dim3(BDIM), 0, stream,
                       x, xb, Wih0, Whh0, bih0, bhh0, Wih1, Whh1, bih1, bhh1,
                       ring, h1buf, h1f, bar);
  } else {
    hipLaunchKernelGGL((lstm2_fused<false>), dim3(NBLK), dim3(BDIM), 0, stream,
                       x, xb, Wih0, Whh0, bih0, bhh0, Wih1, Whh1, bih1, bhh1,
                       ring, h1buf, h1f, bar);
  }
  hipLaunchKernelGGL(dense_out, dim3(250), dim3(256), 0, stream, h1f, Wd, bd,
                     (float*)d_out);
}